// Round 5
// baseline (176.926 us; speedup 1.0000x reference)
//
#include <hip/hip_runtime.h>
#include <math.h>

// Problem constants (match reference)
#define BB 8
#define AA 512
#define NBH 64
#define FF 128
#define GG 50
#define CUTOFF 5.0f

typedef __attribute__((ext_vector_type(8)))  short bf16x8;   // 8 bf16 = 4 VGPRs
typedef __attribute__((ext_vector_type(4)))  float f32x4;    // 16x16 MFMA C/D
typedef __attribute__((ext_vector_type(16))) float f32x16;   // 32x32 MFMA C/D

#define MST 136   // M_s row stride (shorts); with XOR swizzle: reads & writes conflict-free
#define FST 72    // f_s row stride (shorts)

// Packed weight sizes (bf16 elems)
#define WKV_ELEMS (4*8*64*8)   // 16384 : Wk/Wv, 32-col B-frag layout, K=128 (8 steps of 16)
#define WQO_ELEMS (8*4*64*8)   // 16384 : Wq/Wo, 16-col B-frag layout, K=128 (4 steps of 32)
#define WF_ELEMS  (4*4*64*8)   // 8192  : W_filt, 32-col layout, K=64 pad (4 steps of 16)

__device__ __forceinline__ short f2bf(float f) {
    union { float f; unsigned u; } v; v.f = f;
    unsigned r = v.u + 0x7fffu + ((v.u >> 16) & 1u);   // RNE
    return (short)(r >> 16);
}

__device__ __forceinline__ int swz(int n) { return ((n >> 3) & 3) << 3; }  // LDS k-index XOR swizzle

// Sum over the 16-lane DPP row (VALU pipe, no LDS/DS traffic). All lanes get the sum.
__device__ __forceinline__ float row16_sum(float x) {
    int t;
    t = __builtin_amdgcn_update_dpp(0, __float_as_int(x), 0x128, 0xf, 0xf, true); x += __int_as_float(t); // row_ror:8
    t = __builtin_amdgcn_update_dpp(0, __float_as_int(x), 0x124, 0xf, 0xf, true); x += __int_as_float(t); // row_ror:4
    t = __builtin_amdgcn_update_dpp(0, __float_as_int(x), 0x122, 0xf, 0xf, true); x += __int_as_float(t); // row_ror:2
    t = __builtin_amdgcn_update_dpp(0, __float_as_int(x), 0x121, 0xf, 0xf, true); x += __int_as_float(t); // row_ror:1
    return x;
}

// ---------------- prep: pack weights into MFMA B-fragment order ----------------
// 32-col layout (Wk/Wv/Wf): dst[((w*S+s)*64+l)*8+j] = W[16s + (l>>5)*8 + j][32w + (l&31)]
// 16-col layout (Wq/Wo):    dst[((c*4+s)*64+l)*8+j] = W[32s + (l>>4)*8 + j][16c + (l&15)]
__global__ void prep_kernel(const float* __restrict__ Wk,
                            const float* __restrict__ Wv,
                            const float* __restrict__ Wq,
                            const float* __restrict__ Wo,
                            const float* __restrict__ Wf,
                            short* __restrict__ ws)
{
    int gid = blockIdx.x * blockDim.x + threadIdx.x;
    if (gid < 2 * WKV_ELEMS) {
        const float* src = (gid < WKV_ELEMS) ? Wk : Wv;
        int idx = gid & (WKV_ELEMS - 1);
        int j = idx & 7, l = (idx >> 3) & 63, rest = idx >> 9;
        int s = rest & 7, w = rest >> 3;
        int k = 16 * s + ((l >> 5) << 3) + j;
        int n = 32 * w + (l & 31);
        ws[gid] = f2bf(src[k * FF + n]);
    } else if (gid < 2 * WKV_ELEMS + 2 * WQO_ELEMS) {
        int idx2 = gid - 2 * WKV_ELEMS;
        const float* src = (idx2 < WQO_ELEMS) ? Wq : Wo;
        int idx = idx2 & (WQO_ELEMS - 1);
        int j = idx & 7, l = (idx >> 3) & 63, rest = idx >> 9;
        int s = rest & 3, c = rest >> 2;
        int k = 32 * s + (l >> 4) * 8 + j;
        int n = 16 * c + (l & 15);
        ws[gid] = f2bf(src[k * FF + n]);
    } else {
        int idx = gid - 2 * WKV_ELEMS - 2 * WQO_ELEMS;
        int j = idx & 7, l = (idx >> 3) & 63, rest = idx >> 9;
        int s = rest & 3, w = rest >> 2;
        int k = 16 * s + ((l >> 5) << 3) + j;
        int n = 32 * w + (l & 31);
        ws[gid] = (k < GG) ? f2bf(Wf[k * FF + n]) : (short)0;
    }
}

// ---------------- main: one block per atom, 4 waves ----------------
// Wave w owns cols [32w, 32w+32) == heads {2w, 2w+1}, all 64 neighbors.
// 32x32x16 bf16 MFMA layouts (C/D HW-verified m74/m101; A/B standard CDNA):
//   A[m = lane&31][k = (lane>>5)*8 + j]   B[k][n = lane&31]
//   D: col = lane&31, row = (reg&3) + 8*(reg>>2) + 4*(lane>>5)
// 16x16x32 used for q/out broadcast-A matvecs (layouts per m89).
__global__ __launch_bounds__(256, 4)
void tdt_main(const float* __restrict__ x,
              const float* __restrict__ r_ij,
              const float* __restrict__ f_ij,
              const float* __restrict__ b_filt,
              const float* __restrict__ bo,
              const int*   __restrict__ neighbors,
              const int*   __restrict__ nmask,
              const short* __restrict__ WkB,
              const short* __restrict__ WvB,
              const short* __restrict__ WqB,
              const short* __restrict__ WoB,
              const short* __restrict__ WfB,
              float* __restrict__ out)
{
    const int ba   = blockIdx.x;          // 0..4095
    const int b    = ba >> 9;
    const int tid  = threadIdx.x;
    const int lane = tid & 63;
    const int w    = tid >> 6;            // wave 0..3
    const int l15  = lane & 15;
    const int quad = lane >> 4;
    const int l31  = lane & 31;
    const int w5_4 = (lane >> 5) * 4;

    __shared__ short M_s[NBH * MST];      // modulated messages, swizzled   (17.4 KB)
    __shared__ short f_s[NBH * FST];      // f_ij bf16, K-padded, swizzled  ( 9.2 KB)
    __shared__ short x_bf[FF];
    __shared__ short msg_bf[FF];
    __shared__ float x_s[FF];
    __shared__ float C_s[NBH];
    __shared__ int   nbr_s[NBH];

    const float* xb  = x + (size_t)b * AA * FF;
    const size_t bao = (size_t)ba;

    // per-wave neighbor mask as a 64-bit ballot (no LDS reads later)
    unsigned long long mask64 = __ballot(nmask[bao * NBH + lane] != 0);

    // ---------------- phase 0: cooperative staging ----------------
    if (tid < FF) {
        float xv = x[bao * FF + tid];
        x_s[tid]  = xv;
        x_bf[tid] = f2bf(xv);
    }
    if (tid < NBH) {
        float r = r_ij[bao * NBH + tid];
        float c = 0.5f * (__cosf((float)M_PI * r * (1.0f / CUTOFF)) + 1.0f);
        C_s[tid]   = (r < CUTOFF) ? c : 0.0f;
        nbr_s[tid] = neighbors[bao * NBH + tid];
    }
    {
        const float* frow = f_ij + bao * (size_t)(NBH * GG);
        int n = tid / 50;                 // single divide; then incremental
        int g = tid - n * 50;
        for (int it = 0; it < 13; ++it) {
            int idx = tid + it * 256;
            if (idx < NBH * GG)
                f_s[n * FST + (g ^ swz(n))] = f2bf(frow[idx]);
            g += 6; n += 5;
            if (g >= 50) { g -= 50; n += 1; }
        }
        for (int idx = tid; idx < NBH * (64 - GG); idx += 256) {   // zero-pad k=50..63
            int nn = idx / 14;
            int gg = GG + (idx - nn * 14);
            f_s[nn * FST + (gg ^ swz(nn))] = 0;
        }
    }
    __syncthreads();

    // ---------------- phase 1a: q via 16x16x32 MFMA (broadcast-A = x) ----------------
    float qv[2];
    {
        bf16x8 xa[4];
#pragma unroll
        for (int s = 0; s < 4; ++s)
            xa[s] = *(const bf16x8*)&x_bf[s * 32 + quad * 8];
#pragma unroll
        for (int ct = 0; ct < 2; ++ct) {
            int cg = 2 * w + ct;
            f32x4 z = {0.f, 0.f, 0.f, 0.f};
#pragma unroll
            for (int s = 0; s < 4; ++s) {
                bf16x8 bq = *(const bf16x8*)&WqB[((cg * 4 + s) * 64 + lane) * 8];
                z = __builtin_amdgcn_mfma_f32_16x16x32_bf16(xa[s], bq, z, 0, 0, 0);
            }
            qv[ct] = z[0];   // all rows identical; col = cg*16 + l15
        }
    }

    // ---------------- phase 1b: filter 32x32x16 MFMA + modulate + gather -> M_s ------
    {
        f32x16 wacc[2];
#pragma unroll
        for (int mt = 0; mt < 2; ++mt)
#pragma unroll
            for (int r = 0; r < 16; ++r) wacc[mt][r] = 0.0f;
#pragma unroll
        for (int s = 0; s < 4; ++s) {
            bf16x8 bf = *(const bf16x8*)&WfB[((w * 4 + s) * 64 + lane) * 8];
            int kb = 16 * s + ((lane >> 5) << 3);
#pragma unroll
            for (int mt = 0; mt < 2; ++mt) {
                int m = 32 * mt + l31;
                bf16x8 fa = *(const bf16x8*)&f_s[m * FST + (kb ^ swz(m))];
                wacc[mt] = __builtin_amdgcn_mfma_f32_32x32x16_bf16(fa, bf, wacc[mt], 0, 0, 0);
            }
        }
        int   c    = 32 * w + l31;
        float bflt = b_filt[c];
#pragma unroll
        for (int mt = 0; mt < 2; ++mt) {
#pragma unroll
            for (int r = 0; r < 16; ++r) {
                int n = 32 * mt + (r & 3) + 8 * (r >> 2) + w5_4;
                float cn = C_s[n];
                float xv = xb[(size_t)nbr_s[n] * FF + c];   // 2 rows x 128B, coalesced
                M_s[n * MST + (c ^ swz(n))] = f2bf((wacc[mt][r] + bflt) * cn * xv);
            }
        }
    }
    __syncthreads();

    // ---------------- phase 2: k/v via 32x32x16 MFMA (both heads in one col-tile) ----
    f32x16 kacc[2], vacc[2];
#pragma unroll
    for (int mt = 0; mt < 2; ++mt)
#pragma unroll
        for (int r = 0; r < 16; ++r) { kacc[mt][r] = 0.0f; vacc[mt][r] = 0.0f; }
#pragma unroll
    for (int s = 0; s < 8; ++s) {
        bf16x8 bk = *(const bf16x8*)&WkB[((w * 8 + s) * 64 + lane) * 8];
        bf16x8 bv = *(const bf16x8*)&WvB[((w * 8 + s) * 64 + lane) * 8];
        int kb = 16 * s + ((lane >> 5) << 3);
#pragma unroll
        for (int mt = 0; mt < 2; ++mt) {
            int m = 32 * mt + l31;
            bf16x8 ma = *(const bf16x8*)&M_s[m * MST + (kb ^ swz(m))];
            kacc[mt] = __builtin_amdgcn_mfma_f32_32x32x16_bf16(ma, bk, kacc[mt], 0, 0, 0);
            vacc[mt] = __builtin_amdgcn_mfma_f32_32x32x16_bf16(ma, bv, vacc[mt], 0, 0, 0);
        }
    }

    // ---------------- phase 3-5: scores (DPP reduce) + softmax + msg, in-lane --------
    {
        float qvm = qv[(lane >> 4) & 1];          // q[32w + (lane&31)]
        float sc[2][16];
#pragma unroll
        for (int mt = 0; mt < 2; ++mt) {
#pragma unroll
            for (int r = 0; r < 16; ++r) {
                float s = kacc[mt][r] * qvm;
                s = row16_sum(s);                  // sum over the 16 dims of this head
                int n = 32 * mt + (r & 3) + 8 * (r >> 2) + w5_4;
                s *= 0.25f;                        // 1/sqrt(DH)
                sc[mt][r] = ((mask64 >> n) & 1ull) ? s : -1e9f;
            }
        }
        float mx = -1e30f;
#pragma unroll
        for (int mt = 0; mt < 2; ++mt)
#pragma unroll
            for (int r = 0; r < 16; ++r) mx = fmaxf(mx, sc[mt][r]);
        mx = fmaxf(mx, __shfl_xor(mx, 32, 64));    // other half of the 64 neighbors
        float sum = 0.0f;
#pragma unroll
        for (int mt = 0; mt < 2; ++mt)
#pragma unroll
            for (int r = 0; r < 16; ++r) {
                float e = __expf(sc[mt][r] - mx);
                sc[mt][r] = e;
                sum += e;
            }
        sum += __shfl_xor(sum, 32, 64);
        float inv = 1.0f / sum;
        float acc = 0.0f;
#pragma unroll
        for (int mt = 0; mt < 2; ++mt)
#pragma unroll
            for (int r = 0; r < 16; ++r)
                acc = fmaf(sc[mt][r], vacc[mt][r], acc);
        acc += __shfl_xor(acc, 32, 64);
        if (lane < 32) msg_bf[32 * w + l31] = f2bf(acc * inv);
    }
    __syncthreads();

    // ---------------- phase 6: out = msg.Wo + x + bo (16x16x32, broadcast-A) ---------
    {
        bf16x8 mga[4];
#pragma unroll
        for (int s = 0; s < 4; ++s)
            mga[s] = *(const bf16x8*)&msg_bf[s * 32 + quad * 8];
#pragma unroll
        for (int ct = 0; ct < 2; ++ct) {
            int cg = 2 * w + ct;
            f32x4 z = {0.f, 0.f, 0.f, 0.f};
#pragma unroll
            for (int s = 0; s < 4; ++s) {
                bf16x8 bw = *(const bf16x8*)&WoB[((cg * 4 + s) * 64 + lane) * 8];
                z = __builtin_amdgcn_mfma_f32_16x16x32_bf16(mga[s], bw, z, 0, 0, 0);
            }
            if (quad == 0) {
                int col = cg * 16 + l15;
                out[bao * FF + col] = z[0] + x_s[col] + bo[col];
            }
        }
    }
}

extern "C" void kernel_launch(void* const* d_in, const int* in_sizes, int n_in,
                              void* d_out, int out_size, void* d_ws, size_t ws_size,
                              hipStream_t stream) {
    // 0:e 1:x 2:t 3:r_ij 4:f_ij 5:W_filt 6:b_filt 7:Wq 8:Wk 9:Wv 10:Wo 11:bo
    // 12:neighbors 13:neighbor_mask (bool -> int32)
    const float* x      = (const float*)d_in[1];
    const float* r_ij   = (const float*)d_in[3];
    const float* f_ij   = (const float*)d_in[4];
    const float* W_filt = (const float*)d_in[5];
    const float* b_filt = (const float*)d_in[6];
    const float* Wq     = (const float*)d_in[7];
    const float* Wk     = (const float*)d_in[8];
    const float* Wv     = (const float*)d_in[9];
    const float* Wo     = (const float*)d_in[10];
    const float* bo     = (const float*)d_in[11];
    const int*   nbr    = (const int*)d_in[12];
    const int*   msk    = (const int*)d_in[13];
    float* out = (float*)d_out;

    short* ws  = (short*)d_ws;   // 73728 bf16 = 144 KB scratch
    short* WkB = ws;
    short* WvB = ws + WKV_ELEMS;
    short* WqB = ws + 2 * WKV_ELEMS;
    short* WoB = ws + 2 * WKV_ELEMS + WQO_ELEMS;
    short* WfB = ws + 2 * WKV_ELEMS + 2 * WQO_ELEMS;

    int prep_total = 2 * WKV_ELEMS + 2 * WQO_ELEMS + WF_ELEMS;   // 73728 = 288 * 256
    hipLaunchKernelGGL(prep_kernel, dim3(prep_total / 256), dim3(256), 0, stream,
                       Wk, Wv, Wq, Wo, W_filt, ws);
    hipLaunchKernelGGL(tdt_main, dim3(BB * AA), dim3(256), 0, stream,
                       x, r_ij, f_ij, b_filt, bo, nbr, msk,
                       WkB, WvB, WqB, WoB, WfB, out);
}